// Round 1
// baseline (2873.860 us; speedup 1.0000x reference)
//
#include <hip/hip_runtime.h>
#include <math.h>

#define BT 65536   // B*T
#define TSEQ 256
#define VOCAB 65

// ---------------- embed + positional encoding ----------------
__global__ __launch_bounds__(256)
void embed_kernel(const int* __restrict__ inp,
                  const float* __restrict__ emb,
                  float* __restrict__ x) {
    int idx = blockIdx.x * 256 + threadIdx.x;   // over BT*64
    int tok = idx >> 6;
    int e = idx & 63;
    int t = tok & (TSEQ - 1);
    int id = inp[tok];
    int i = e >> 1;
    // div_term[i] = exp(-(2i) * ln(10000)/64)
    float div = expf(-(2.0f * (float)i) * 0.14391156934706f);
    float ang = (float)t * div;
    float pe = (e & 1) ? cosf(ang) : sinf(ang);
    x[idx] = emb[id * 64 + e] + pe;
}

// ---------------- generic f32 GEMM ----------------
// C[N,M] = (ACCUM? C : 0) + A[N,K] @ W[K,M] (+bias) (ReLU optional)
// block: 256 threads -> 64 rows x 64 cols tile, 4x4 per thread.
template<int K, bool RELU, bool ACCUM>
__global__ __launch_bounds__(256)
void gemm_kernel(const float* __restrict__ A,
                 const float* __restrict__ W, int ldw,
                 const float* __restrict__ bias,
                 float* __restrict__ C, int ldc, int M) {
    __shared__ float At[64][68];   // [k][row], pad 68 keeps b128 reads aligned+conflict-free
    __shared__ float Ws[64][68];   // [k][col]
    const int t = threadIdx.x;
    const int r0 = blockIdx.x * 64;
    const int c0 = blockIdx.y * 64;
    const int tr = (t >> 4) * 4;   // 0..60
    const int tc = (t & 15) * 4;   // 0..60
    float acc[4][4] = {};
    for (int kc = 0; kc < K; kc += 64) {
        #pragma unroll
        for (int i = 0; i < 16; ++i) {
            int idx = t + 256 * i;
            int r = idx >> 6;
            int k = idx & 63;
            At[k][r] = A[(size_t)(r0 + r) * K + (kc + k)];
        }
        #pragma unroll
        for (int i = 0; i < 16; ++i) {
            int idx = t + 256 * i;
            int k = idx >> 6;
            int c = idx & 63;
            float wv = 0.0f;
            if (c0 + c < M) wv = W[(size_t)(kc + k) * ldw + (c0 + c)];
            Ws[k][c] = wv;
        }
        __syncthreads();
        #pragma unroll
        for (int k = 0; k < 64; ++k) {
            float4 a = *(const float4*)&At[k][tr];
            float4 w = *(const float4*)&Ws[k][tc];
            acc[0][0] = fmaf(a.x, w.x, acc[0][0]);
            acc[0][1] = fmaf(a.x, w.y, acc[0][1]);
            acc[0][2] = fmaf(a.x, w.z, acc[0][2]);
            acc[0][3] = fmaf(a.x, w.w, acc[0][3]);
            acc[1][0] = fmaf(a.y, w.x, acc[1][0]);
            acc[1][1] = fmaf(a.y, w.y, acc[1][1]);
            acc[1][2] = fmaf(a.y, w.z, acc[1][2]);
            acc[1][3] = fmaf(a.y, w.w, acc[1][3]);
            acc[2][0] = fmaf(a.z, w.x, acc[2][0]);
            acc[2][1] = fmaf(a.z, w.y, acc[2][1]);
            acc[2][2] = fmaf(a.z, w.z, acc[2][2]);
            acc[2][3] = fmaf(a.z, w.w, acc[2][3]);
            acc[3][0] = fmaf(a.w, w.x, acc[3][0]);
            acc[3][1] = fmaf(a.w, w.y, acc[3][1]);
            acc[3][2] = fmaf(a.w, w.z, acc[3][2]);
            acc[3][3] = fmaf(a.w, w.w, acc[3][3]);
        }
        __syncthreads();
    }
    #pragma unroll
    for (int i = 0; i < 4; ++i) {
        size_t r = (size_t)(r0 + tr + i);
        #pragma unroll
        for (int j = 0; j < 4; ++j) {
            int c = c0 + tc + j;
            if (c < M) {
                float v = acc[i][j];
                if (bias) v += bias[c];
                if (RELU) v = fmaxf(v, 0.0f);
                if (ACCUM) v += C[r * ldc + c];
                C[r * ldc + c] = v;
            }
        }
    }
}

// ---------------- causal attention, one block per (b,h) ----------------
__global__ __launch_bounds__(256)
void attn_kernel(const float* __restrict__ q, const float* __restrict__ k,
                 const float* __restrict__ v, float* __restrict__ o) {
    __shared__ float Ks[256][8];
    __shared__ float Vs[256][8];
    int b = blockIdx.x >> 3;
    int h = blockIdx.x & 7;
    int t = threadIdx.x;                 // query row
    size_t base = ((size_t)b * 256) * 64 + h * 8;
    const float* kp = k + base + (size_t)t * 64;
    const float* vp = v + base + (size_t)t * 64;
    *(float4*)&Ks[t][0] = *(const float4*)kp;
    *(float4*)&Ks[t][4] = *(const float4*)(kp + 4);
    *(float4*)&Vs[t][0] = *(const float4*)vp;
    *(float4*)&Vs[t][4] = *(const float4*)(vp + 4);
    __syncthreads();
    const float* qp = q + base + (size_t)t * 64;
    float4 q0 = *(const float4*)qp;
    float4 q1 = *(const float4*)(qp + 4);
    const float scale = 0.35355339059327373f;   // 1/sqrt(8)
    float m = -1e30f, l = 0.0f;
    float4 a0 = {0, 0, 0, 0}, a1 = {0, 0, 0, 0};
    for (int j = 0; j <= t; ++j) {               // causal: skip j > t
        float4 k0 = *(const float4*)&Ks[j][0];
        float4 k1 = *(const float4*)&Ks[j][4];
        float s = q0.x * k0.x + q0.y * k0.y + q0.z * k0.z + q0.w * k0.w
                + q1.x * k1.x + q1.y * k1.y + q1.z * k1.z + q1.w * k1.w;
        s *= scale;
        float nm = fmaxf(m, s);
        float f = __expf(m - nm);
        float p = __expf(s - nm);
        l = l * f + p;
        float4 v0 = *(const float4*)&Vs[j][0];
        float4 v1 = *(const float4*)&Vs[j][4];
        a0.x = a0.x * f + p * v0.x; a0.y = a0.y * f + p * v0.y;
        a0.z = a0.z * f + p * v0.z; a0.w = a0.w * f + p * v0.w;
        a1.x = a1.x * f + p * v1.x; a1.y = a1.y * f + p * v1.y;
        a1.z = a1.z * f + p * v1.z; a1.w = a1.w * f + p * v1.w;
        m = nm;
    }
    float inv = 1.0f / l;
    float* op = o + base + (size_t)t * 64;
    float4 r0 = {a0.x * inv, a0.y * inv, a0.z * inv, a0.w * inv};
    float4 r1 = {a1.x * inv, a1.y * inv, a1.z * inv, a1.w * inv};
    *(float4*)op = r0;
    *(float4*)(op + 4) = r1;
}

// ---------------- fused residual add + LayerNorm (wave per row) ----------------
__global__ __launch_bounds__(256)
void addln_kernel(float* __restrict__ x, const float* __restrict__ p,
                  const float* __restrict__ g, const float* __restrict__ bta) {
    int row = blockIdx.x * 4 + (threadIdx.x >> 6);
    int e = threadIdx.x & 63;
    size_t idx = (size_t)row * 64 + e;
    float v = x[idx] + p[idx];
    float s = v, s2 = v * v;
    #pragma unroll
    for (int mask = 1; mask < 64; mask <<= 1) {
        s  += __shfl_xor(s, mask, 64);
        s2 += __shfl_xor(s2, mask, 64);
    }
    float mu = s * (1.0f / 64.0f);
    float var = s2 * (1.0f / 64.0f) - mu * mu;
    x[idx] = (v - mu) * rsqrtf(var + 1e-5f) * g[e] + bta[e];
}

// ---------------- loss: per-row logsumexp (wave per row) ----------------
__global__ __launch_bounds__(256)
void loss_row_kernel(const float* __restrict__ logits, const int* __restrict__ labels,
                     float* __restrict__ row_loss) {
    int row = blockIdx.x * 4 + (threadIdx.x >> 6);
    int e = threadIdx.x & 63;
    const float* lr = logits + (size_t)row * VOCAB;
    float v0 = lr[e];
    float v1 = (e == 0) ? lr[64] : -1e30f;
    float mx = fmaxf(v0, v1);
    #pragma unroll
    for (int mask = 1; mask < 64; mask <<= 1) mx = fmaxf(mx, __shfl_xor(mx, mask, 64));
    float se = __expf(v0 - mx);
    if (e == 0) se += __expf(v1 - mx);
    #pragma unroll
    for (int mask = 1; mask < 64; mask <<= 1) se += __shfl_xor(se, mask, 64);
    if (e == 0) {
        float lse = mx + logf(se);
        row_loss[row] = lse - lr[labels[row]];
    }
}

__global__ __launch_bounds__(256)
void loss_reduce_kernel(const float* __restrict__ row_loss, float* __restrict__ out) {
    float s = 0.0f;
    for (int i = threadIdx.x; i < BT; i += 256) s += row_loss[i];
    #pragma unroll
    for (int mask = 1; mask < 64; mask <<= 1) s += __shfl_xor(s, mask, 64);
    __shared__ float sm[4];
    if ((threadIdx.x & 63) == 0) sm[threadIdx.x >> 6] = s;
    __syncthreads();
    if (threadIdx.x == 0)
        out[0] = (sm[0] + sm[1] + sm[2] + sm[3]) * (1.0f / (float)BT);
}

// ---------------- host ----------------
extern "C" void kernel_launch(void* const* d_in, const int* in_sizes, int n_in,
                              void* d_out, int out_size, void* d_ws, size_t ws_size,
                              hipStream_t stream) {
    const int*   inputs = (const int*)d_in[0];
    const int*   labels = (const int*)d_in[1];
    const float* emb  = (const float*)d_in[2];
    const float* Wq   = (const float*)d_in[3];
    const float* bq   = (const float*)d_in[4];
    const float* Wk   = (const float*)d_in[5];
    const float* bk   = (const float*)d_in[6];
    const float* Wv   = (const float*)d_in[7];
    const float* bv   = (const float*)d_in[8];
    const float* Wo   = (const float*)d_in[9];
    const float* bo   = (const float*)d_in[10];
    const float* ln1g = (const float*)d_in[11];
    const float* ln1b = (const float*)d_in[12];
    const float* ln2g = (const float*)d_in[13];
    const float* ln2b = (const float*)d_in[14];
    const float* W1   = (const float*)d_in[15];
    const float* b1   = (const float*)d_in[16];
    const float* W2   = (const float*)d_in[17];
    const float* b2   = (const float*)d_in[18];
    const float* Wout = (const float*)d_in[19];
    const float* bout = (const float*)d_in[20];

    float* logits = (float*)d_out;                   // [BT, 65]
    float* loss   = logits + (size_t)BT * VOCAB;     // scalar

    const size_t BUF = (size_t)BT * 64 * sizeof(float);   // 16 MB
    char* ws = (char*)d_ws;
    float* x   = (float*)(ws);
    float* qb  = (float*)(ws + BUF);
    float* kb  = (float*)(ws + 2 * BUF);
    float* vb  = (float*)(ws + 3 * BUF);
    float* ao  = (float*)(ws + 4 * BUF);
    float* hid = (float*)(ws + 5 * BUF);             // [BT, 128], 32 MB
    float* rloss = hid;                              // reused after FFN is done

    dim3 blk(256);

    embed_kernel<<<BT * 64 / 256, blk, 0, stream>>>(inputs, emb, x);

    for (int l = 0; l < 6; ++l) {
        const float* wq = Wq + (size_t)l * 4096;
        const float* wk = Wk + (size_t)l * 4096;
        const float* wv = Wv + (size_t)l * 4096;
        const float* wo = Wo + (size_t)l * 4096;
        gemm_kernel<64, false, false><<<dim3(1024, 1), blk, 0, stream>>>(x, wq, 64, bq + l * 64, qb, 64, 64);
        gemm_kernel<64, false, false><<<dim3(1024, 1), blk, 0, stream>>>(x, wk, 64, bk + l * 64, kb, 64, 64);
        gemm_kernel<64, false, false><<<dim3(1024, 1), blk, 0, stream>>>(x, wv, 64, bv + l * 64, vb, 64, 64);
        attn_kernel<<<2048, blk, 0, stream>>>(qb, kb, vb, ao);
        gemm_kernel<64, false, false><<<dim3(1024, 1), blk, 0, stream>>>(ao, wo, 64, bo + l * 64, qb, 64, 64);
        addln_kernel<<<BT / 4, blk, 0, stream>>>(x, qb, ln1g + l * 64, ln1b + l * 64);
        // FFN split into two 128-wide halves to bound workspace
        for (int hh = 0; hh < 2; ++hh) {
            const float* w1 = W1 + (size_t)l * 16384 + hh * 128;          // [64,256] cols hh*128..
            const float* w2 = W2 + (size_t)l * 16384 + (size_t)hh * 128 * 64; // [256,64] rows hh*128..
            gemm_kernel<64, true, false><<<dim3(1024, 2), blk, 0, stream>>>(x, w1, 256, b1 + l * 256 + hh * 128, hid, 128, 128);
            if (hh == 0)
                gemm_kernel<128, false, false><<<dim3(1024, 1), blk, 0, stream>>>(hid, w2, 64, b2 + l * 64, qb, 64, 64);
            else
                gemm_kernel<128, false, true><<<dim3(1024, 1), blk, 0, stream>>>(hid, w2, 64, nullptr, qb, 64, 64);
        }
        addln_kernel<<<BT / 4, blk, 0, stream>>>(x, qb, ln2g + l * 64, ln2b + l * 64);
    }

    gemm_kernel<64, false, false><<<dim3(1024, 2), blk, 0, stream>>>(x, Wout, VOCAB, bout, logits, VOCAB, VOCAB);
    loss_row_kernel<<<BT / 4, blk, 0, stream>>>(logits, labels, rloss);
    loss_reduce_kernel<<<1, blk, 0, stream>>>(rloss, loss);
}

// Round 2
// 401.516 us; speedup vs baseline: 7.1575x; 7.1575x over previous
//
#include <hip/hip_runtime.h>
#include <math.h>

#define TSEQ 256
#define VOCAB 65
#define NBATCH 256

typedef __attribute__((ext_vector_type(8))) short bf16x8;
typedef __attribute__((ext_vector_type(4))) float f32x4;

#define MFMA16(a, b, c) __builtin_amdgcn_mfma_f32_16x16x32_bf16((a), (b), (c), 0, 0, 0)

__device__ __forceinline__ unsigned short f2b(float f) {
    union { float f; unsigned u; } v; v.f = f;
    unsigned r = (v.u + 0x7fffu + ((v.u >> 16) & 1u)) >> 16;
    return (unsigned short)r;
}
__device__ __forceinline__ float b2f(unsigned short h) {
    union { unsigned u; float f; } v; v.u = ((unsigned)h) << 16;
    return v.f;
}

// ---------------- weight transpose + bf16 convert ----------------
// wbuf layout (shorts): wqkvt 6*[3][64][64] @0 ; wot 6*[64][64] @73728 ;
// w1t 6*[256][64] @98304 ; w2t 6*[64][256] @196608 ; woutt [80][64] @294912
__global__ __launch_bounds__(256)
void prep_kernel(const float* __restrict__ Wq, const float* __restrict__ Wk,
                 const float* __restrict__ Wv, const float* __restrict__ Wo,
                 const float* __restrict__ W1, const float* __restrict__ W2,
                 const float* __restrict__ Wout, unsigned short* __restrict__ wbuf) {
    int l = blockIdx.y;
    int idx = blockIdx.x * 256 + threadIdx.x;
    if (l < 6) {
        float v; unsigned short* dst;
        if (idx < 12288) {                    // wqkvt [mat][m][k] = Wmat[l][k][m]
            int mat = idx >> 12, m = (idx >> 6) & 63, k = idx & 63;
            const float* W = mat == 0 ? Wq : (mat == 1 ? Wk : Wv);
            v = W[l * 4096 + k * 64 + m];
            dst = wbuf + l * 12288 + idx;
        } else if (idx < 16384) {             // wot [m][k] = Wo[l][k][m]
            int j = idx - 12288; int m = j >> 6, k = j & 63;
            v = Wo[l * 4096 + k * 64 + m];
            dst = wbuf + 73728 + l * 4096 + j;
        } else if (idx < 32768) {             // w1t [m(256)][k(64)] = W1[l][k][m]
            int j = idx - 16384; int m = j >> 6, k = j & 63;
            v = W1[l * 16384 + k * 256 + m];
            dst = wbuf + 98304 + l * 16384 + j;
        } else {                              // w2t [m(64)][k(256)] = W2[l][k][m]
            int j = idx - 32768; int m = j >> 8, k = j & 255;
            v = W2[l * 16384 + k * 64 + m];
            dst = wbuf + 196608 + l * 16384 + j;
        }
        *dst = f2b(v);
    } else {
        if (idx < 5120) {                     // woutt [m(80)][k(64)], rows>=65 zero
            int m = idx >> 6, k = idx & 63;
            float v = (m < 65) ? Wout[k * 65 + m] : 0.f;
            wbuf[294912 + idx] = f2b(v);
        }
    }
}

// ---------------- the whole transformer, one block per batch element ----------------
__global__ __launch_bounds__(512, 2)
void tf_kernel(const int* __restrict__ inp, const int* __restrict__ labels,
               const float* __restrict__ emb,
               const float* __restrict__ bq, const float* __restrict__ bk,
               const float* __restrict__ bv, const float* __restrict__ bo,
               const float* __restrict__ ln1g, const float* __restrict__ ln1b,
               const float* __restrict__ ln2g, const float* __restrict__ ln2b,
               const float* __restrict__ b1, const float* __restrict__ b2,
               const float* __restrict__ bout,
               const unsigned short* __restrict__ wbuf,
               float* __restrict__ out_logits, float* __restrict__ partials) {
    __shared__ __attribute__((aligned(16))) unsigned short res[256][66];  // residual x, bf16
    __shared__ __attribute__((aligned(16))) unsigned short xb[256][72];   // mfma A operand
    __shared__ __attribute__((aligned(16))) unsigned short q2[256][20];   // q pair (scaled)
    __shared__ __attribute__((aligned(16))) unsigned short k2[256][20];   // k pair
    __shared__ __attribute__((aligned(16))) unsigned short vt[16][264];   // v pair, transposed [d][key]
    __shared__ __attribute__((aligned(16))) unsigned short pc[8][16][40]; // per-wave P chunk
    __shared__ __attribute__((aligned(16))) unsigned short hb[256][40];   // FFN hidden chunk
    __shared__ float red[8];

    const unsigned short* wqkvt = wbuf;
    const unsigned short* wot   = wbuf + 73728;
    const unsigned short* w1t   = wbuf + 98304;
    const unsigned short* w2t   = wbuf + 196608;
    const unsigned short* woutt = wbuf + 294912;

    const int b = blockIdx.x;
    const int tid = threadIdx.x;
    const int w = tid >> 6;
    const int lane = tid & 63;
    const int cc = lane & 15;
    const int gg = lane >> 4;

    const bf16x8 zf = {0, 0, 0, 0, 0, 0, 0, 0};
    const bf16x8 ones = {(short)0x3F80, (short)0x3F80, (short)0x3F80, (short)0x3F80,
                         (short)0x3F80, (short)0x3F80, (short)0x3F80, (short)0x3F80};

    // ---------- embed + positional ----------
    for (int u = 0; u < 32; ++u) {
        int idx = tid + 512 * u;                 // 0..16383
        int r = idx >> 6, e = idx & 63;
        int id = inp[b * 256 + r];
        int i2 = e >> 1;
        float div = expf(-(float)(2 * i2) * 0.14391156831212788f);
        float ang = (float)r * div;
        float pe = (e & 1) ? cosf(ang) : sinf(ang);
        float v = emb[id * 64 + e] + pe;
        unsigned short bv16 = f2b(v);
        res[r][e] = bv16;
        xb[r][e] = bv16;
    }
    __syncthreads();

    for (int l = 0; l < 6; ++l) {
        const unsigned short* Wqkv = wqkvt + l * 12288;
        float ost[16][4];

        // ================= attention =================
        #pragma unroll 4
        for (int p = 0; p < 4; ++p) {
            __syncthreads();   // previous pair's q2/k2/vt reads complete
            // ---- QKV gemm for pair p: wave w -> m-tiles {2w, 2w+1}, mats q,k,v ----
            bf16x8 af[2][2];
            #pragma unroll
            for (int mi = 0; mi < 2; ++mi) {
                int row = 16 * (2 * w + mi) + cc;
                af[mi][0] = *(const bf16x8*)&xb[row][0 + 8 * gg];
                af[mi][1] = *(const bf16x8*)&xb[row][32 + 8 * gg];
            }
            #pragma unroll
            for (int mat = 0; mat < 3; ++mat) {
                const unsigned short* Wt = Wqkv + mat * 4096;
                bf16x8 bf0 = *(const bf16x8*)&Wt[(16 * p + cc) * 64 + 8 * gg];
                bf16x8 bf1 = *(const bf16x8*)&Wt[(16 * p + cc) * 64 + 32 + 8 * gg];
                const float* bias = (mat == 0 ? bq : (mat == 1 ? bk : bv)) + l * 64;
                float bb = bias[16 * p + cc];
                #pragma unroll
                for (int mi = 0; mi < 2; ++mi) {
                    f32x4 c = {0.f, 0.f, 0.f, 0.f};
                    c = MFMA16(af[mi][0], bf0, c);
                    c = MFMA16(af[mi][1], bf1, c);
                    int mrow = 16 * (2 * w + mi);
                    #pragma unroll
                    for (int r = 0; r < 4; ++r) {
                        float v = c[r] + bb;
                        int row = mrow + 4 * gg + r;
                        if (mat == 0)      q2[row][cc] = f2b(v * 0.35355339059327373f);
                        else if (mat == 1) k2[row][cc] = f2b(v);
                        else               vt[cc][row] = f2b(v);
                    }
                }
            }
            __syncthreads();   // q2/k2/vt ready

            // ---- per head: wave-local flash attention ----
            #pragma unroll
            for (int hh = 0; hh < 2; ++hh) {
                const int hoff = hh * 8;
                const int h = 2 * p + hh;
                #pragma unroll
                for (int s = 0; s < 2; ++s) {
                    int a_ = (w + h) & 7;
                    int i = s ? (15 - a_) : a_;
                    bf16x8 qa = zf;
                    if (gg == 0) qa = *(const bf16x8*)&q2[16 * i + cc][hoff];
                    f32x4 o = {0.f, 0.f, 0.f, 0.f};
                    int nchunk = (i >> 1) + 1;
                    for (int jc = 0; jc < nchunk; ++jc) {
                        #pragma unroll
                        for (int jt2 = 0; jt2 < 2; ++jt2) {
                            int jt = 2 * jc + jt2;
                            float pv[4];
                            if (jt <= i) {
                                bf16x8 kb = zf;
                                if (gg == 0) kb = *(const bf16x8*)&k2[16 * jt + cc][hoff];
                                f32x4 sc = {0.f, 0.f, 0.f, 0.f};
                                sc = MFMA16(qa, kb, sc);
                                #pragma unroll
                                for (int r = 0; r < 4; ++r) {
                                    float pp = __expf(sc[r]);          // scores tiny: no max
                                    if (jt == i && cc > 4 * gg + r) pp = 0.f;  // causal
                                    pv[r] = pp;
                                }
                            } else {
                                pv[0] = pv[1] = pv[2] = pv[3] = 0.f;
                            }
                            #pragma unroll
                            for (int r = 0; r < 4; ++r)
                                pc[w][4 * gg + r][jt2 * 16 + cc] = f2b(pv[r]);
                        }
                        asm volatile("" ::: "memory");
                        bf16x8 pa = *(const bf16x8*)&pc[w][cc][8 * gg];
                        bf16x8 vb;
                        if (cc < 8)      vb = *(const bf16x8*)&vt[hoff + cc][32 * jc + 8 * gg];
                        else if (cc == 8) vb = ones;   // rowsum column
                        else             vb = zf;
                        o = MFMA16(pa, vb, o);
                        asm volatile("" ::: "memory");
                    }
                    #pragma unroll
                    for (int r = 0; r < 4; ++r) {
                        float rs = __shfl(o[r], (lane & 48) + 8, 64);
                        ost[h * 2 + s][r] = o[r] / rs;
                    }
                }
            }
        }
        // ---- write O (held in regs) into xb; x copies no longer needed ----
        #pragma unroll 8
        for (int h = 0; h < 8; ++h) {
            #pragma unroll
            for (int s = 0; s < 2; ++s) {
                int a_ = (w + h) & 7;
                int i = s ? (15 - a_) : a_;
                if (cc < 8) {
                    #pragma unroll
                    for (int r = 0; r < 4; ++r)
                        xb[16 * i + 4 * gg + r][8 * h + cc] = f2b(ost[h * 2 + s][r]);
                }
            }
        }
        __syncthreads();

        // ================= attn out projection: res += xb @ Wo + bo =================
        {
            const unsigned short* Wt = wot + l * 4096;
            int n = w & 3;
            bf16x8 bf0 = *(const bf16x8*)&Wt[(16 * n + cc) * 64 + 8 * gg];
            bf16x8 bf1 = *(const bf16x8*)&Wt[(16 * n + cc) * 64 + 32 + 8 * gg];
            float bb = bo[l * 64 + 16 * n + cc];
            #pragma unroll
            for (int mi = 0; mi < 8; ++mi) {
                int mt = 8 * (w >> 2) + mi;
                bf16x8 a0 = *(const bf16x8*)&xb[16 * mt + cc][8 * gg];
                bf16x8 a1 = *(const bf16x8*)&xb[16 * mt + cc][32 + 8 * gg];
                f32x4 c = {0.f, 0.f, 0.f, 0.f};
                c = MFMA16(a0, bf0, c);
                c = MFMA16(a1, bf1, c);
                #pragma unroll
                for (int r = 0; r < 4; ++r) {
                    int row = 16 * mt + 4 * gg + r, col = 16 * n + cc;
                    res[row][col] = f2b(b2f(res[row][col]) + c[r] + bb);
                }
            }
        }
        __syncthreads();
        // ================= LN1 =================
        {
            int r = tid >> 1, q = tid & 1;
            float s = 0.f, s2 = 0.f;
            for (int j = 0; j < 32; ++j) {
                float x = b2f(res[r][q + 2 * j]);
                s += x; s2 += x * x;
            }
            s += __shfl_xor(s, 1, 64);
            s2 += __shfl_xor(s2, 1, 64);
            float mu = s * 0.015625f;
            float var = s2 * 0.015625f - mu * mu;
            float rstd = rsqrtf(var + 1e-5f);
            for (int j = 0; j < 32; ++j) {
                int e = q + 2 * j;
                float xn = (b2f(res[r][e]) - mu) * rstd * ln1g[l * 64 + e] + ln1b[l * 64 + e];
                unsigned short xv = f2b(xn);
                res[r][e] = xv; xb[r][e] = xv;
            }
        }
        __syncthreads();

        // ================= FFN =================
        f32x4 facc[8];
        #pragma unroll
        for (int t = 0; t < 8; ++t) facc[t] = {0.f, 0.f, 0.f, 0.f};
        for (int ch = 0; ch < 8; ++ch) {
            {   // FFN1 chunk: hidden cols 32ch..32ch+31, relu -> hb
                const unsigned short* Wt = w1t + l * 16384;
                int n = w & 1;
                int gcol = 32 * ch + 16 * n + cc;
                bf16x8 bf0 = *(const bf16x8*)&Wt[gcol * 64 + 8 * gg];
                bf16x8 bf1 = *(const bf16x8*)&Wt[gcol * 64 + 32 + 8 * gg];
                float bb = b1[l * 256 + gcol];
                #pragma unroll
                for (int mi = 0; mi < 4; ++mi) {
                    int mt = 4 * (w >> 1) + mi;
                    bf16x8 a0 = *(const bf16x8*)&xb[16 * mt + cc][8 * gg];
                    bf16x8 a1 = *(const bf16x8*)&xb[16 * mt + cc][32 + 8 * gg];
                    f32x4 c = {0.f, 0.f, 0.f, 0.f};
                    c = MFMA16(a0, bf0, c);
                    c = MFMA16(a1, bf1, c);
                    #pragma unroll
                    for (int r = 0; r < 4; ++r)
                        hb[16 * mt + 4 * gg + r][16 * n + cc] = f2b(fmaxf(c[r] + bb, 0.f));
                }
            }
            __syncthreads();
            {   // FFN2 accumulate
                const unsigned short* Wt = w2t + l * 16384;
                int n = w & 3;
                bf16x8 bf0 = *(const bf16x8*)&Wt[(16 * n + cc) * 256 + 32 * ch + 8 * gg];
                #pragma unroll
                for (int mi = 0; mi < 8; ++mi) {
                    int mt = 8 * (w >> 2) + mi;
                    bf16x8 a0 = *(const bf16x8*)&hb[16 * mt + cc][8 * gg];
                    facc[mi] = MFMA16(a0, bf0, facc[mi]);
                }
            }
            __syncthreads();
        }
        {   // FFN2 epilogue: res += facc + b2
            int n = w & 3;
            float bb = b2[l * 64 + 16 * n + cc];
            #pragma unroll
            for (int mi = 0; mi < 8; ++mi) {
                int mt = 8 * (w >> 2) + mi;
                #pragma unroll
                for (int r = 0; r < 4; ++r) {
                    int row = 16 * mt + 4 * gg + r, col = 16 * n + cc;
                    res[row][col] = f2b(b2f(res[row][col]) + facc[mi][r] + bb);
                }
            }
        }
        __syncthreads();
        // ================= LN2 =================
        {
            int r = tid >> 1, q = tid & 1;
            float s = 0.f, s2 = 0.f;
            for (int j = 0; j < 32; ++j) {
                float x = b2f(res[r][q + 2 * j]);
                s += x; s2 += x * x;
            }
            s += __shfl_xor(s, 1, 64);
            s2 += __shfl_xor(s2, 1, 64);
            float mu = s * 0.015625f;
            float var = s2 * 0.015625f - mu * mu;
            float rstd = rsqrtf(var + 1e-5f);
            for (int j = 0; j < 32; ++j) {
                int e = q + 2 * j;
                float xn = (b2f(res[r][e]) - mu) * rstd * ln2g[l * 64 + e] + ln2b[l * 64 + e];
                unsigned short xv = f2b(xn);
                res[r][e] = xv; xb[r][e] = xv;
            }
        }
        __syncthreads();
    } // layers

    // ================= logits =================
    #pragma unroll
    for (int t = 0; t < 10; ++t) {
        int id = w + 8 * t;             // 0..79
        int n = id >> 4, mt = id & 15;
        bf16x8 bf0 = *(const bf16x8*)&woutt[(16 * n + cc) * 64 + 8 * gg];
        bf16x8 bf1 = *(const bf16x8*)&woutt[(16 * n + cc) * 64 + 32 + 8 * gg];
        bf16x8 a0 = *(const bf16x8*)&xb[16 * mt + cc][8 * gg];
        bf16x8 a1 = *(const bf16x8*)&xb[16 * mt + cc][32 + 8 * gg];
        f32x4 c = {0.f, 0.f, 0.f, 0.f};
        c = MFMA16(a0, bf0, c);
        c = MFMA16(a1, bf1, c);
        int col = 16 * n + cc;
        if (col < 65) {
            float bb = bout[col];
            #pragma unroll
            for (int r = 0; r < 4; ++r) {
                int row = 16 * mt + 4 * gg + r;
                float v = c[r] + bb;
                out_logits[((size_t)b * 256 + row) * 65 + col] = v;
                res[row][col] = f2b(v);   // stage for loss
            }
        }
    }
    __syncthreads();

    // ================= loss partial =================
    {
        int r = tid >> 1, q = tid & 1;
        float sum = 0.f;
        for (int c = q; c < 65; c += 2) sum += __expf(b2f(res[r][c]));
        sum += __shfl_xor(sum, 1, 64);
        float nll = 0.f;
        if (q == 0) {
            int lab = labels[b * 256 + r];
            nll = logf(sum) - b2f(res[r][lab]);
        }
        #pragma unroll
        for (int m = 1; m < 64; m <<= 1) nll += __shfl_xor(nll, m, 64);
        if (lane == 0) red[w] = nll;
        __syncthreads();
        if (tid == 0) {
            float s = 0.f;
            #pragma unroll
            for (int i = 0; i < 8; ++i) s += red[i];
            partials[b] = s;
        }
    }
}

__global__ __launch_bounds__(64)
void loss_reduce(const float* __restrict__ partials, float* __restrict__ out) {
    int t = threadIdx.x;
    float s = partials[t] + partials[t + 64] + partials[t + 128] + partials[t + 192];
    #pragma unroll
    for (int m = 1; m < 64; m <<= 1) s += __shfl_xor(s, m, 64);
    if (t == 0) out[0] = s * (1.f / 65536.f);
}

// ---------------- host ----------------
extern "C" void kernel_launch(void* const* d_in, const int* in_sizes, int n_in,
                              void* d_out, int out_size, void* d_ws, size_t ws_size,
                              hipStream_t stream) {
    const int*   inputs = (const int*)d_in[0];
    const int*   labels = (const int*)d_in[1];
    const float* emb  = (const float*)d_in[2];
    const float* Wq   = (const float*)d_in[3];
    const float* bq   = (const float*)d_in[4];
    const float* Wk   = (const float*)d_in[5];
    const float* bk   = (const float*)d_in[6];
    const float* Wv   = (const float*)d_in[7];
    const float* bv   = (const float*)d_in[8];
    const float* Wo   = (const float*)d_in[9];
    const float* bo   = (const float*)d_in[10];
    const float* ln1g = (const float*)d_in[11];
    const float* ln1b = (const float*)d_in[12];
    const float* ln2g = (const float*)d_in[13];
    const float* ln2b = (const float*)d_in[14];
    const float* W1   = (const float*)d_in[15];
    const float* b1   = (const float*)d_in[16];
    const float* W2   = (const float*)d_in[17];
    const float* b2   = (const float*)d_in[18];
    const float* Wout = (const float*)d_in[19];
    const float* bout = (const float*)d_in[20];

    float* logits = (float*)d_out;
    float* loss   = logits + (size_t)65536 * 65;

    float* partials = (float*)d_ws;
    unsigned short* wbuf = (unsigned short*)((char*)d_ws + 1024);

    prep_kernel<<<dim3(192, 7), 256, 0, stream>>>(Wq, Wk, Wv, Wo, W1, W2, Wout, wbuf);
    tf_kernel<<<NBATCH, 512, 0, stream>>>(inputs, labels, emb,
                                          bq, bk, bv, bo,
                                          ln1g, ln1b, ln2g, ln2b,
                                          b1, b2, bout,
                                          wbuf, logits, partials);
    loss_reduce<<<1, 64, 0, stream>>>(partials, loss);
}